// Round 6
// baseline (184.150 us; speedup 1.0000x reference)
//
#include <hip/hip_runtime.h>
#include <cstdint>

#define B_  4
#define S_  4096
#define DIN 1024
#define DH  128
#define SCALE 0.08838834764831845f

typedef short bf16x8 __attribute__((ext_vector_type(8)));
typedef float f32x4 __attribute__((ext_vector_type(4)));
typedef unsigned short u16;
typedef unsigned int   u32;

#define MFMA16(a, b, c) __builtin_amdgcn_mfma_f32_16x16x32_bf16(a, b, c, 0, 0, 0)

#define GLOAD_LDS16(g, l) __builtin_amdgcn_global_load_lds( \
    (const __attribute__((address_space(1))) void*)(g),     \
    (__attribute__((address_space(3))) void*)(l), 16, 0, 0)

__device__ inline u16 bf16_rn(float f) {
    union { float f; u32 u; } v; v.f = f;
    u32 r = v.u + 0x7FFFu + ((v.u >> 16) & 1u);
    return (u16)(r >> 16);
}
__device__ inline float bf16_f(u16 h) {
    union { u32 u; float f; } v; v.u = ((u32)h) << 16; return v.f;
}
__device__ inline u32 pk2(float a, float b) {
    return (u32)bf16_rn(a) | ((u32)bf16_rn(b) << 16);
}
__device__ inline void split2(float a, float b, u32& hi, u32& lo) {
    u32 ua = __builtin_bit_cast(u32, a), ub = __builtin_bit_cast(u32, b);
    u32 ha = ua & 0xFFFF0000u, hb = ub & 0xFFFF0000u;
    hi = (ua >> 16) | hb;
    float la = a - __builtin_bit_cast(float, ha);
    float lb = b - __builtin_bit_cast(float, hb);
    lo = (u32)bf16_rn(la) | ((u32)bf16_rn(lb) << 16);
}

// ---------------- Kernel 0: W convert/split/transpose/swizzle (unchanged) ----------------
__global__ __launch_bounds__(256) void wconv(
    const float* __restrict__ Wq, const float* __restrict__ Wk, const float* __restrict__ Wv,
    u16* __restrict__ whi, u16* __restrict__ wlo)
{
    int bid = blockIdx.x;                       // 0..1535
    int mat = bid >> 9;
    int i = ((bid & 511) << 8) | threadIdx.x;
    int k = i >> 7, n = i & 127;
    const float* W = (mat == 0) ? Wq : (mat == 1 ? Wk : Wv);
    float v = W[i];
    if (mat == 0) v *= SCALE;
    u32 u = __builtin_bit_cast(u32, v);
    float lo = v - __builtin_bit_cast(float, u & 0xFFFF0000u);
    int kt = k >> 6, kq = (k >> 3) & 7, j = k & 7;
    size_t pos = (((size_t)(mat * 16 + kt) * 128 + n) << 6)
               + (size_t)(((kq ^ (n & 7)) << 3) + j);
    whi[pos] = (u16)(u >> 16);
    wlo[pos] = bf16_rn(lo);
}

// ---------------- Kernel 1: fused QKV v3 ----------------
// grid 256 x 256 thr (4 waves). Block: 64 rows x 128 cols x ALL 3 mats.
// Wave (wr,wc): rows 32*wr..+31 (rt=2 frags), cols 64*wc..+63 (nt=4).
// x: per-lane direct global loads + in-register hi/lo split (no LDS).
// W: LDS double-buffered 32-k half-steps, 5 parts x 8KB, granule-major layout.
__global__ __launch_bounds__(256) void qkv_v3(
    const float* __restrict__ x,
    const u16* __restrict__ wThi, const u16* __restrict__ wTlo,
    u16* __restrict__ qhi, u16* __restrict__ qlo,
    u16* __restrict__ khi, u16* __restrict__ klo, u16* __restrict__ vt)
{
    __shared__ __align__(16) char lds[81920];   // 2 bufs x 40960

    const int t    = threadIdx.x;
    const int row0 = blockIdx.x * 64;
    const int lane = t & 63, wave = t >> 6;
    const int l15  = lane & 15, g = lane >> 4;
    const int wr   = wave >> 1, wc = wave & 1;

    f32x4 accq[2][4], acck[2][4], accv[2][4];
    #pragma unroll
    for (int rt = 0; rt < 2; ++rt)
        #pragma unroll
        for (int nt = 0; nt < 4; ++nt)
            #pragma unroll
            for (int r = 0; r < 4; ++r) {
                accq[rt][nt][r] = 0.f; acck[rt][nt][r] = 0.f; accv[rt][nt][r] = 0.f;
            }

    const char* WH = (const char*)wThi;
    const char* WL = (const char*)wTlo;

    // stage one 32-k half-step of W (all 5 parts) into buf
    auto stage = [&](int bufi, int s) {
        const int kt = s >> 1, h = s & 1;
        char* d = lds + bufi * 40960;
        #pragma unroll
        for (int c = 0; c < 2; ++c) {
            const int gi  = t + 256 * c;
            const int kq2 = gi >> 7, n = gi & 127;
            const int swz = (((h << 2) + kq2) ^ (n & 7)) << 4;
            const int no  = n << 7;
            GLOAD_LDS16(WH + (((size_t)(kt)      << 14) + no + swz), d         + gi * 16);
            GLOAD_LDS16(WL + (((size_t)(kt)      << 14) + no + swz), d +  8192 + gi * 16);
            GLOAD_LDS16(WH + (((size_t)(16 + kt) << 14) + no + swz), d + 16384 + gi * 16);
            GLOAD_LDS16(WL + (((size_t)(16 + kt) << 14) + no + swz), d + 24576 + gi * 16);
            GLOAD_LDS16(WH + (((size_t)(32 + kt) << 14) + no + swz), d + 32768 + gi * 16);
        }
    };

    const float* xp0 = x + (size_t)(row0 + 32 * wr + l15) * DIN + 8 * g;
    const float* xp1 = xp0 + (size_t)16 * DIN;

    stage(0, 0);
    __syncthreads();

    int buf = 0;
    for (int s = 0; s < 32; ++s) {
        if (s < 31) stage(buf ^ 1, s + 1);

        // ---- x fragments: 8 fp32 per rt, split hi/lo in-register ----
        bf16x8 xh[2], xl[2];
        {
            float4 fa = *(const float4*)(xp0 + 32 * s);
            float4 fb = *(const float4*)(xp0 + 32 * s + 4);
            uint4 H, L;
            split2(fa.x, fa.y, H.x, L.x); split2(fa.z, fa.w, H.y, L.y);
            split2(fb.x, fb.y, H.z, L.z); split2(fb.z, fb.w, H.w, L.w);
            xh[0] = __builtin_bit_cast(bf16x8, H);
            xl[0] = __builtin_bit_cast(bf16x8, L);
        }
        {
            float4 fa = *(const float4*)(xp1 + 32 * s);
            float4 fb = *(const float4*)(xp1 + 32 * s + 4);
            uint4 H, L;
            split2(fa.x, fa.y, H.x, L.x); split2(fa.z, fa.w, H.y, L.y);
            split2(fb.x, fb.y, H.z, L.z); split2(fb.z, fb.w, H.w, L.w);
            xh[1] = __builtin_bit_cast(bf16x8, H);
            xl[1] = __builtin_bit_cast(bf16x8, L);
        }

        const char* wb = lds + buf * 40960;
        #pragma unroll
        for (int nt = 0; nt < 4; ++nt) {
            const int n  = 64 * wc + 16 * nt + l15;
            const int wo = (g << 11) + (n << 4);
            bf16x8 qwh = *(const bf16x8*)(wb + wo);
            bf16x8 qwl = *(const bf16x8*)(wb +  8192 + wo);
            bf16x8 kwh = *(const bf16x8*)(wb + 16384 + wo);
            bf16x8 kwl = *(const bf16x8*)(wb + 24576 + wo);
            bf16x8 vwh = *(const bf16x8*)(wb + 32768 + wo);
            #pragma unroll
            for (int rt = 0; rt < 2; ++rt) {
                accq[rt][nt] = MFMA16(xh[rt], qwh, accq[rt][nt]);
                accq[rt][nt] = MFMA16(xl[rt], qwh, accq[rt][nt]);
                accq[rt][nt] = MFMA16(xh[rt], qwl, accq[rt][nt]);
                acck[rt][nt] = MFMA16(xh[rt], kwh, acck[rt][nt]);
                acck[rt][nt] = MFMA16(xl[rt], kwh, acck[rt][nt]);
                acck[rt][nt] = MFMA16(xh[rt], kwl, acck[rt][nt]);
                accv[rt][nt] = MFMA16(xh[rt], vwh, accv[rt][nt]);
            }
        }
        __syncthreads();
        buf ^= 1;
    }

    // ---- epilogue: emit flash-ready layouts (identical formulas to verified r5) ----
    #pragma unroll
    for (int rt = 0; rt < 2; ++rt) {
        #pragma unroll
        for (int reg = 0; reg < 4; ++reg) {
            int r  = row0 + 32 * wr + 16 * rt + 4 * g + reg;
            int bb = r >> 12, sr = r & 4095, kt = sr >> 6, kr = sr & 63;
            #pragma unroll
            for (int nt = 0; nt < 4; ++nt) {
                int c = 64 * wc + 16 * nt + l15;
                {   // Q: row-major hi/lo
                    float v = accq[rt][nt][reg];
                    u32 u = __builtin_bit_cast(u32, v);
                    float lo = v - __builtin_bit_cast(float, u & 0xFFFF0000u);
                    size_t o = (size_t)r * DH + c;
                    qhi[o] = (u16)(u >> 16);
                    qlo[o] = bf16_rn(lo);
                }
                {   // K: tiled + granule swizzle
                    float v = acck[rt][nt][reg];
                    u32 u = __builtin_bit_cast(u32, v);
                    float lo = v - __builtin_bit_cast(float, u & 0xFFFF0000u);
                    size_t o = ((size_t)(bb * 64 + kt) * 64 + kr) * 128
                             + (((c >> 3) ^ (kr & 15)) << 3) + (c & 7);
                    khi[o] = (u16)(u >> 16);
                    klo[o] = bf16_rn(lo);
                }
                {   // V: transposed tile + granule swizzle
                    float v = accv[rt][nt][reg];
                    size_t o = ((size_t)(bb * 64 + kt) * 128 + c) * 64
                             + (((kr >> 3) ^ (c & 7)) << 3) + (kr & 7);
                    vt[o] = bf16_rn(v);
                }
            }
        }
    }
}

// ---------------- Kernel 2: flash attention (unchanged from round 5) ----------------
__global__ __launch_bounds__(512, 2) void flash4(
    const u16* __restrict__ qhi, const u16* __restrict__ qlo,
    const u16* __restrict__ khi, const u16* __restrict__ klo,
    const u16* __restrict__ vt,
    u16* __restrict__ opart, float2* __restrict__ ml)
{
    __shared__ __align__(16) char smem[2 * 49152];

    const int tid  = threadIdx.x;
    const int wave = tid >> 6, lane = tid & 63;
    const int l15  = lane & 15, g = lane >> 4;
    const int bid  = blockIdx.x;
    const int pair = bid & 15, qt = bid >> 4;
    const int b = pair >> 2, z = pair & 3;

    const int q0row = b * S_ + qt * 256 + wave * 32;

    bf16x8 qh[2][4], ql[2][4];
    #pragma unroll
    for (int h = 0; h < 2; ++h)
        #pragma unroll
        for (int ks = 0; ks < 4; ++ks) {
            size_t qa = (size_t)(q0row + 16 * h + l15) * DH + 32 * ks + 8 * g;
            qh[h][ks] = *(const bf16x8*)(qhi + qa);
            ql[h][ks] = *(const bf16x8*)(qlo + qa);
        }

    f32x4 O0[8], O1[8];
    #pragma unroll
    for (int dt = 0; dt < 8; ++dt)
        #pragma unroll
        for (int r = 0; r < 4; ++r) { O0[dt][r] = 0.f; O1[dt][r] = 0.f; }

    float m0 = -3.0e38f, l0 = 0.f, m1 = -3.0e38f, l1 = 0.f;

    int koff[4];
    #pragma unroll
    for (int ks = 0; ks < 4; ++ks)
        koff[ks] = (((4 * ks + g) ^ l15) << 4) + (l15 << 8);
    int voff[2];
    #pragma unroll
    for (int kw = 0; kw < 2; ++kw)
        voff[kw] = (((4 * kw + g) ^ (l15 & 7)) << 4);

    const char* kbase = (const char*)(khi + (size_t)b * 64 * 8192);
    const char* lbase = (const char*)(klo + (size_t)b * 64 * 8192);
    const char* vbase = (const char*)(vt  + (size_t)b * 64 * 8192);
    const int kt0 = z * 16;

    auto stage = [&](int bufi, int ktl) {
        const char* sk = kbase + (size_t)(kt0 + ktl) * 16384;
        const char* sl = lbase + (size_t)(kt0 + ktl) * 16384;
        const char* sv = vbase + (size_t)(kt0 + ktl) * 16384;
        char* dk = smem + bufi * 49152;
        #pragma unroll
        for (int c = 0; c < 2; ++c) {
            int o = tid * 16 + c * 8192;
            GLOAD_LDS16(sk + o, dk + o);
            GLOAD_LDS16(sl + o, dk + 16384 + o);
            GLOAD_LDS16(sv + o, dk + 32768 + o);
        }
    };

    stage(0, 0);
    __syncthreads();

    int buf = 0;
    for (int ktl = 0; ktl < 16; ++ktl) {
        if (ktl < 15) stage(buf ^ 1, ktl + 1);

        const char* bk = smem + buf * 49152;
        const char* bl = bk + 16384;
        const char* bv = bk + 32768;

        f32x4 s0[4], s1[4];
        #pragma unroll
        for (int nt = 0; nt < 4; ++nt)
            #pragma unroll
            for (int r = 0; r < 4; ++r) { s0[nt][r] = 0.f; s1[nt][r] = 0.f; }

        #pragma unroll
        for (int ks = 0; ks < 4; ++ks) {
            #pragma unroll
            for (int nt = 0; nt < 4; ++nt) {
                bf16x8 kh = *(const bf16x8*)(bk + nt * 4096 + koff[ks]);
                bf16x8 kl = *(const bf16x8*)(bl + nt * 4096 + koff[ks]);
                s0[nt] = MFMA16(kh, qh[0][ks], s0[nt]);
                s0[nt] = MFMA16(kh, ql[0][ks], s0[nt]);
                s0[nt] = MFMA16(kl, qh[0][ks], s0[nt]);
                s1[nt] = MFMA16(kh, qh[1][ks], s1[nt]);
                s1[nt] = MFMA16(kh, ql[1][ks], s1[nt]);
                s1[nt] = MFMA16(kl, qh[1][ks], s1[nt]);
            }
        }

        u32 pk0[4][2], pk1[4][2];
        float fsc0, fsc1;
        {   // softmax half 0
            float mloc = -3.0e38f;
            #pragma unroll
            for (int nt = 0; nt < 4; ++nt)
                #pragma unroll
                for (int r = 0; r < 4; ++r) mloc = fmaxf(mloc, s0[nt][r]);
            mloc = fmaxf(mloc, __shfl_xor(mloc, 16));
            mloc = fmaxf(mloc, __shfl_xor(mloc, 32));
            float mnew = fmaxf(m0, mloc);
            fsc0 = __expf(m0 - mnew);
            m0 = mnew;
            float ps = 0.f;
            #pragma unroll
            for (int nt = 0; nt < 4; ++nt) {
                float p0 = __expf(s0[nt][0] - mnew);
                float p1 = __expf(s0[nt][1] - mnew);
                float p2 = __expf(s0[nt][2] - mnew);
                float p3 = __expf(s0[nt][3] - mnew);
                ps += (p0 + p1) + (p2 + p3);
                pk0[nt][0] = pk2(p0, p1);
                pk0[nt][1] = pk2(p2, p3);
            }
            ps += __shfl_xor(ps, 16);
            ps += __shfl_xor(ps, 32);
            l0 = l0 * fsc0 + ps;
        }
        {   // softmax half 1
            float mloc = -3.0e38f;
            #pragma unroll
            for (int nt = 0; nt < 4; ++nt)
                #pragma unroll
                for (int r = 0; r < 4; ++r) mloc = fmaxf(mloc, s1[nt][r]);
            mloc = fmaxf(mloc, __shfl_xor(mloc, 16));
            mloc = fmaxf(mloc, __shfl_xor(mloc, 32));
            float mnew = fmaxf(m1, mloc);
            fsc1 = __expf(m1 - mnew);
            m1 = mnew;
            float ps = 0.f;
            #pragma unroll
            for (int nt = 0; nt < 4; ++nt) {
                float p0 = __expf(s1[nt][0] - mnew);
                float p1 = __expf(s1[nt][1] - mnew);
                float p2 = __expf(s1[nt][2] - mnew);
                float p3 = __expf(s1[nt][3] - mnew);
                ps += (p0 + p1) + (p2 + p3);
                pk1[nt][0] = pk2(p0, p1);
                pk1[nt][1] = pk2(p2, p3);
            }
            ps += __shfl_xor(ps, 16);
            ps += __shfl_xor(ps, 32);
            l1 = l1 * fsc1 + ps;
        }

        float fr0[4], fr1[4];
        #pragma unroll
        for (int r = 0; r < 4; ++r) {
            fr0[r] = __shfl(fsc0, 4 * g + r);
            fr1[r] = __shfl(fsc1, 4 * g + r);
        }
        #pragma unroll
        for (int dt = 0; dt < 8; ++dt)
            #pragma unroll
            for (int r = 0; r < 4; ++r) {
                O0[dt][r] *= fr0[r];
                O1[dt][r] *= fr1[r];
            }

        const int s0l = l15 | ((2 * (g & 1)) << 4);
        const int s1l = s0l + 16;
        const int hiH = g >> 1;
        #pragma unroll
        for (int kw = 0; kw < 2; ++kw) {
            u32 a0, a1, a2, a3, c0, c1, c2, c3;
            {
                u32 x0 = __shfl(pk0[2 * kw][0], s0l), y0 = __shfl(pk0[2 * kw + 1][0], s0l);
                u32 x1 = __shfl(pk0[2 * kw][1], s0l), y1 = __shfl(pk0[2 * kw + 1][1], s0l);
                u32 x2 = __shfl(pk0[2 * kw][0], s1l), y2 = __shfl(pk0[2 * kw + 1][0], s1l);
                u32 x3 = __shfl(pk0[2 * kw][1], s1l), y3 = __shfl(pk0[2 * kw + 1][1], s1l);
                a0 = hiH ? y0 : x0; a1 = hiH ? y1 : x1;
                a2 = hiH ? y2 : x2; a3 = hiH ? y3 : x3;
            }
            {
                u32 x0 = __shfl(pk1[2 * kw][0], s0l), y0 = __shfl(pk1[2 * kw + 1][0], s0l);
                u32 x1 = __shfl(pk1[2 * kw][1], s0l), y1 = __shfl(pk1[2 * kw + 1][1], s0l);
                u32 x2 = __shfl(pk1[2 * kw][0], s1l), y2 = __shfl(pk1[2 * kw + 1][0], s1l);
                u32 x3 = __shfl(pk1[2 * kw][1], s1l), y3 = __shfl(pk1[2 * kw + 1][1], s1l);
                c0 = hiH ? y0 : x0; c1 = hiH ? y1 : x1;
                c2 = hiH ? y2 : x2; c3 = hiH ? y3 : x3;
            }
            union { u32 w[4]; bf16x8 v; } pa, pb;
            pa.w[0] = a0; pa.w[1] = a1; pa.w[2] = a2; pa.w[3] = a3;
            pb.w[0] = c0; pb.w[1] = c1; pb.w[2] = c2; pb.w[3] = c3;
            #pragma unroll
            for (int dt = 0; dt < 8; ++dt) {
                bf16x8 vf = *(const bf16x8*)(bv + (16 * dt + l15) * 128 + voff[kw]);
                O0[dt] = MFMA16(pa.v, vf, O0[dt]);
                O1[dt] = MFMA16(pb.v, vf, O1[dt]);
            }
        }

        __syncthreads();
        buf ^= 1;
    }

    u16* op = opart + ((size_t)z * 16384 + q0row) * DH;
    #pragma unroll
    for (int dt = 0; dt < 8; ++dt)
        #pragma unroll
        for (int r = 0; r < 4; ++r) {
            op[(size_t)(4 * g + r) * DH + 16 * dt + l15]      = bf16_rn(O0[dt][r]);
            op[(size_t)(16 + 4 * g + r) * DH + 16 * dt + l15] = bf16_rn(O1[dt][r]);
        }
    if (lane < 16) {
        ml[(size_t)z * 16384 + q0row + lane]      = make_float2(m0, l0);
        ml[(size_t)z * 16384 + q0row + 16 + lane] = make_float2(m1, l1);
    }
}

// ---------------- Kernel 3: merge the four kt-quarters (unchanged) ----------------
__global__ __launch_bounds__(256) void merge4(
    const u16* __restrict__ op, const float2* __restrict__ ml, float* __restrict__ O)
{
    int row = blockIdx.x * 16 + (threadIdx.x >> 4);
    int dq  = (threadIdx.x & 15) * 8;
    float2 a[4];
    #pragma unroll
    for (int zz = 0; zz < 4; ++zz) a[zz] = ml[(size_t)zz * 16384 + row];
    float M = fmaxf(fmaxf(a[0].x, a[1].x), fmaxf(a[2].x, a[3].x));
    float w[4], den = 0.f;
    #pragma unroll
    for (int zz = 0; zz < 4; ++zz) {
        w[zz] = __expf(a[zz].x - M);
        den += a[zz].y * w[zz];
    }
    float inv = 1.0f / den;
    float acc[8];
    #pragma unroll
    for (int j = 0; j < 8; ++j) acc[j] = 0.f;
    #pragma unroll
    for (int zz = 0; zz < 4; ++zz) {
        const u16* p = op + ((size_t)zz * 16384 + row) * DH + dq;
        bf16x8 vv = *(const bf16x8*)p;
        #pragma unroll
        for (int j = 0; j < 8; ++j) acc[j] += w[zz] * bf16_f((u16)vv[j]);
    }
    float4 oa, ob;
    oa.x = acc[0] * inv; oa.y = acc[1] * inv; oa.z = acc[2] * inv; oa.w = acc[3] * inv;
    ob.x = acc[4] * inv; ob.y = acc[5] * inv; ob.z = acc[6] * inv; ob.w = acc[7] * inv;
    *(float4*)(O + (size_t)row * DH + dq)     = oa;
    *(float4*)(O + (size_t)row * DH + dq + 4) = ob;
}

extern "C" void kernel_launch(void* const* d_in, const int* in_sizes, int n_in,
                              void* d_out, int out_size, void* d_ws, size_t ws_size,
                              hipStream_t stream) {
    const float* x  = (const float*)d_in[0];
    const float* Wq = (const float*)d_in[1];
    const float* Wk = (const float*)d_in[2];
    const float* Wv = (const float*)d_in[3];
    float* out = (float*)d_out;

    const size_t SZ = (size_t)B_ * S_ * DH;     // 2,097,152 elems
    u16* qhi = (u16*)d_ws;
    u16* qlo = qhi + SZ;
    u16* khi = qlo + SZ;
    u16* klo = khi + SZ;
    u16* vtp = klo + SZ;
    u16* whi = vtp + SZ;                        // 393,216 elems each (dead after qkv)
    u16* wlo = whi + 393216;
    u16*    opart = whi;                        // overlay: 4 * 16384 * 128 bf16 = 16 MB
    float2* mlp   = (float2*)((char*)whi + (size_t)4 * 16384 * 128 * 2);

    wconv<<<1536, 256, 0, stream>>>(Wq, Wk, Wv, whi, wlo);
    qkv_v3<<<256, 256, 0, stream>>>(x, whi, wlo, qhi, qlo, khi, klo, vtp);
    flash4<<<256, 512, 0, stream>>>(qhi, qlo, khi, klo, vtp, opart, mlp);
    merge4<<<1024, 256, 0, stream>>>(opart, mlp, out);
}

// Round 7
// 151.662 us; speedup vs baseline: 1.2142x; 1.2142x over previous
//
#include <hip/hip_runtime.h>
#include <cstdint>

#define B_  4
#define S_  4096
#define DIN 1024
#define DH  128
#define SCALE 0.08838834764831845f

typedef short bf16x8 __attribute__((ext_vector_type(8)));
typedef float f32x4 __attribute__((ext_vector_type(4)));
typedef unsigned short u16;
typedef unsigned int   u32;

#define MFMA16(a, b, c) __builtin_amdgcn_mfma_f32_16x16x32_bf16(a, b, c, 0, 0, 0)

#define GLOAD_LDS16(g, l) __builtin_amdgcn_global_load_lds( \
    (const __attribute__((address_space(1))) void*)(g),     \
    (__attribute__((address_space(3))) void*)(l), 16, 0, 0)

__device__ inline u16 bf16_rn(float f) {
    union { float f; u32 u; } v; v.f = f;
    u32 r = v.u + 0x7FFFu + ((v.u >> 16) & 1u);
    return (u16)(r >> 16);
}
__device__ inline float bf16_f(u16 h) {
    union { u32 u; float f; } v; v.u = ((u32)h) << 16; return v.f;
}
__device__ inline u32 pk2(float a, float b) {
    return (u32)bf16_rn(a) | ((u32)bf16_rn(b) << 16);
}
__device__ inline void split2(float a, float b, u32& hi, u32& lo) {
    u32 ua = __builtin_bit_cast(u32, a), ub = __builtin_bit_cast(u32, b);
    u32 ha = ua & 0xFFFF0000u, hb = ub & 0xFFFF0000u;
    hi = (ua >> 16) | hb;
    float la = a - __builtin_bit_cast(float, ha);
    float lb = b - __builtin_bit_cast(float, hb);
    lo = (u32)bf16_rn(la) | ((u32)bf16_rn(lb) << 16);
}

// ---------------- Kernel 0: wconv2 — emit the exact LDS staging image ----------------
// wpack[s(32)][p(5)][gi(512)] of 16B granules; gi = kq2*128 + n;
// granule holds W'[32s + 8*kq2 + j][n], j=0..7.  p: 0=Qhi 1=Qlo 2=Khi 3=Klo 4=Vrn.
__global__ __launch_bounds__(256) void wconv2(
    const float* __restrict__ Wq, const float* __restrict__ Wk, const float* __restrict__ Wv,
    u16* __restrict__ wpack)
{
    int id  = blockIdx.x * 256 + threadIdx.x;   // 0..81919
    int s   = id / 2560;
    int rem = id % 2560;
    int p   = rem >> 9;
    int gi  = rem & 511;
    int n   = gi & 127, kq2 = gi >> 7;
    const float* W = (p < 2) ? Wq : (p < 4) ? Wk : Wv;
    int k0 = 32 * s + 8 * kq2;
    u16 o[8];
    #pragma unroll
    for (int j = 0; j < 8; ++j) {
        float v = W[(size_t)(k0 + j) * DH + n];
        if (p < 2) v *= SCALE;
        if (p == 4) {
            o[j] = bf16_rn(v);                       // V: round-to-nearest
        } else {
            u32 u = __builtin_bit_cast(u32, v);
            if ((p & 1) == 0) o[j] = (u16)(u >> 16); // hi: trunc
            else o[j] = bf16_rn(v - __builtin_bit_cast(float, u & 0xFFFF0000u));
        }
    }
    u16* dst = wpack + (size_t)id * 8;
    *(uint4*)dst = *(uint4*)o;
}

// ---------------- Kernel 1: fused QKV v4 ----------------
// grid 256 x 256 thr (4 waves). Block: 64 rows x 128 cols x all 3 mats.
// x: direct global->reg loads, prefetched one step ahead, split in-register.
// W: wpack staged contiguously (coalesced) into double-buffered LDS, layout
//    identical to the round-6-verified image; MFMA reads unchanged.
__global__ __launch_bounds__(256) void qkv_v4(
    const float* __restrict__ x, const u16* __restrict__ wpack,
    u16* __restrict__ qhi, u16* __restrict__ qlo,
    u16* __restrict__ khi, u16* __restrict__ klo, u16* __restrict__ vt)
{
    __shared__ __align__(16) char lds[81920];   // 2 bufs x 40960

    const int t    = threadIdx.x;
    const int row0 = blockIdx.x * 64;
    const int lane = t & 63, wave = t >> 6;
    const int l15  = lane & 15, g = lane >> 4;
    const int wr   = wave >> 1, wc = wave & 1;

    f32x4 accq[2][4], acck[2][4], accv[2][4];
    #pragma unroll
    for (int rt = 0; rt < 2; ++rt)
        #pragma unroll
        for (int nt = 0; nt < 4; ++nt)
            #pragma unroll
            for (int r = 0; r < 4; ++r) {
                accq[rt][nt][r] = 0.f; acck[rt][nt][r] = 0.f; accv[rt][nt][r] = 0.f;
            }

    const char* WP = (const char*)wpack;
    auto stage = [&](int bufi, int s) {
        char* d = lds + bufi * 40960;
        const char* src = WP + (size_t)s * 40960;
        #pragma unroll
        for (int c = 0; c < 10; ++c) {
            int o = t * 16 + c * 4096;
            GLOAD_LDS16(src + o, d + o);
        }
    };

    const float* xp0 = x + (size_t)(row0 + 32 * wr + l15) * DIN + 8 * g;
    const float* xp1 = xp0 + (size_t)16 * DIN;

    // prefetch x for step 0
    float4 ca0 = *(const float4*)(xp0);
    float4 cb0 = *(const float4*)(xp0 + 4);
    float4 ca1 = *(const float4*)(xp1);
    float4 cb1 = *(const float4*)(xp1 + 4);

    stage(0, 0);
    __syncthreads();

    int buf = 0;
    for (int s = 0; s < 32; ++s) {
        if (s < 31) stage(buf ^ 1, s + 1);

        float4 na0, nb0, na1, nb1;
        if (s < 31) {
            na0 = *(const float4*)(xp0 + 32 * (s + 1));
            nb0 = *(const float4*)(xp0 + 32 * (s + 1) + 4);
            na1 = *(const float4*)(xp1 + 32 * (s + 1));
            nb1 = *(const float4*)(xp1 + 32 * (s + 1) + 4);
        }

        bf16x8 xh[2], xl[2];
        {
            uint4 H, L;
            split2(ca0.x, ca0.y, H.x, L.x); split2(ca0.z, ca0.w, H.y, L.y);
            split2(cb0.x, cb0.y, H.z, L.z); split2(cb0.z, cb0.w, H.w, L.w);
            xh[0] = __builtin_bit_cast(bf16x8, H);
            xl[0] = __builtin_bit_cast(bf16x8, L);
        }
        {
            uint4 H, L;
            split2(ca1.x, ca1.y, H.x, L.x); split2(ca1.z, ca1.w, H.y, L.y);
            split2(cb1.x, cb1.y, H.z, L.z); split2(cb1.z, cb1.w, H.w, L.w);
            xh[1] = __builtin_bit_cast(bf16x8, H);
            xl[1] = __builtin_bit_cast(bf16x8, L);
        }

        const char* wb = lds + buf * 40960;
        #pragma unroll
        for (int nt = 0; nt < 4; ++nt) {
            const int n  = 64 * wc + 16 * nt + l15;
            const int wo = (g << 11) + (n << 4);
            bf16x8 qwh = *(const bf16x8*)(wb + wo);
            bf16x8 qwl = *(const bf16x8*)(wb +  8192 + wo);
            bf16x8 kwh = *(const bf16x8*)(wb + 16384 + wo);
            bf16x8 kwl = *(const bf16x8*)(wb + 24576 + wo);
            bf16x8 vwh = *(const bf16x8*)(wb + 32768 + wo);
            #pragma unroll
            for (int rt = 0; rt < 2; ++rt) {
                accq[rt][nt] = MFMA16(xh[rt], qwh, accq[rt][nt]);
                accq[rt][nt] = MFMA16(xl[rt], qwh, accq[rt][nt]);
                accq[rt][nt] = MFMA16(xh[rt], qwl, accq[rt][nt]);
                acck[rt][nt] = MFMA16(xh[rt], kwh, acck[rt][nt]);
                acck[rt][nt] = MFMA16(xl[rt], kwh, acck[rt][nt]);
                acck[rt][nt] = MFMA16(xh[rt], kwl, acck[rt][nt]);
                accv[rt][nt] = MFMA16(xh[rt], vwh, accv[rt][nt]);
            }
        }
        __syncthreads();
        if (s < 31) { ca0 = na0; cb0 = nb0; ca1 = na1; cb1 = nb1; }
        buf ^= 1;
    }

    // ---- epilogue: emit flash-ready layouts (identical formulas, r5/r6-verified) ----
    #pragma unroll
    for (int rt = 0; rt < 2; ++rt) {
        #pragma unroll
        for (int reg = 0; reg < 4; ++reg) {
            int r  = row0 + 32 * wr + 16 * rt + 4 * g + reg;
            int bb = r >> 12, sr = r & 4095, kt = sr >> 6, kr = sr & 63;
            #pragma unroll
            for (int nt = 0; nt < 4; ++nt) {
                int c = 64 * wc + 16 * nt + l15;
                {   // Q: row-major hi/lo
                    float v = accq[rt][nt][reg];
                    u32 u = __builtin_bit_cast(u32, v);
                    float lo = v - __builtin_bit_cast(float, u & 0xFFFF0000u);
                    size_t o = (size_t)r * DH + c;
                    qhi[o] = (u16)(u >> 16);
                    qlo[o] = bf16_rn(lo);
                }
                {   // K: tiled + granule swizzle
                    float v = acck[rt][nt][reg];
                    u32 u = __builtin_bit_cast(u32, v);
                    float lo = v - __builtin_bit_cast(float, u & 0xFFFF0000u);
                    size_t o = ((size_t)(bb * 64 + kt) * 64 + kr) * 128
                             + (((c >> 3) ^ (kr & 15)) << 3) + (c & 7);
                    khi[o] = (u16)(u >> 16);
                    klo[o] = bf16_rn(lo);
                }
                {   // V: transposed tile + granule swizzle
                    float v = accv[rt][nt][reg];
                    size_t o = ((size_t)(bb * 64 + kt) * 128 + c) * 64
                             + (((kr >> 3) ^ (c & 7)) << 3) + (kr & 7);
                    vt[o] = bf16_rn(v);
                }
            }
        }
    }
}

// ---------------- Kernel 2: flash attention (unchanged, r5-verified) ----------------
__global__ __launch_bounds__(512, 2) void flash4(
    const u16* __restrict__ qhi, const u16* __restrict__ qlo,
    const u16* __restrict__ khi, const u16* __restrict__ klo,
    const u16* __restrict__ vt,
    u16* __restrict__ opart, float2* __restrict__ ml)
{
    __shared__ __align__(16) char smem[2 * 49152];

    const int tid  = threadIdx.x;
    const int wave = tid >> 6, lane = tid & 63;
    const int l15  = lane & 15, g = lane >> 4;
    const int bid  = blockIdx.x;
    const int pair = bid & 15, qt = bid >> 4;
    const int b = pair >> 2, z = pair & 3;

    const int q0row = b * S_ + qt * 256 + wave * 32;

    bf16x8 qh[2][4], ql[2][4];
    #pragma unroll
    for (int h = 0; h < 2; ++h)
        #pragma unroll
        for (int ks = 0; ks < 4; ++ks) {
            size_t qa = (size_t)(q0row + 16 * h + l15) * DH + 32 * ks + 8 * g;
            qh[h][ks] = *(const bf16x8*)(qhi + qa);
            ql[h][ks] = *(const bf16x8*)(qlo + qa);
        }

    f32x4 O0[8], O1[8];
    #pragma unroll
    for (int dt = 0; dt < 8; ++dt)
        #pragma unroll
        for (int r = 0; r < 4; ++r) { O0[dt][r] = 0.f; O1[dt][r] = 0.f; }

    float m0 = -3.0e38f, l0 = 0.f, m1 = -3.0e38f, l1 = 0.f;

    int koff[4];
    #pragma unroll
    for (int ks = 0; ks < 4; ++ks)
        koff[ks] = (((4 * ks + g) ^ l15) << 4) + (l15 << 8);
    int voff[2];
    #pragma unroll
    for (int kw = 0; kw < 2; ++kw)
        voff[kw] = (((4 * kw + g) ^ (l15 & 7)) << 4);

    const char* kbase = (const char*)(khi + (size_t)b * 64 * 8192);
    const char* lbase = (const char*)(klo + (size_t)b * 64 * 8192);
    const char* vbase = (const char*)(vt  + (size_t)b * 64 * 8192);
    const int kt0 = z * 16;

    auto stage = [&](int bufi, int ktl) {
        const char* sk = kbase + (size_t)(kt0 + ktl) * 16384;
        const char* sl = lbase + (size_t)(kt0 + ktl) * 16384;
        const char* sv = vbase + (size_t)(kt0 + ktl) * 16384;
        char* dk = smem + bufi * 49152;
        #pragma unroll
        for (int c = 0; c < 2; ++c) {
            int o = tid * 16 + c * 8192;
            GLOAD_LDS16(sk + o, dk + o);
            GLOAD_LDS16(sl + o, dk + 16384 + o);
            GLOAD_LDS16(sv + o, dk + 32768 + o);
        }
    };

    stage(0, 0);
    __syncthreads();

    int buf = 0;
    for (int ktl = 0; ktl < 16; ++ktl) {
        if (ktl < 15) stage(buf ^ 1, ktl + 1);

        const char* bk = smem + buf * 49152;
        const char* bl = bk + 16384;
        const char* bv = bk + 32768;

        f32x4 s0[4], s1[4];
        #pragma unroll
        for (int nt = 0; nt < 4; ++nt)
            #pragma unroll
            for (int r = 0; r < 4; ++r) { s0[nt][r] = 0.f; s1[nt][r] = 0.f; }

        #pragma unroll
        for (int ks = 0; ks < 4; ++ks) {
            #pragma unroll
            for (int nt = 0; nt < 4; ++nt) {
                bf16x8 kh = *(const bf16x8*)(bk + nt * 4096 + koff[ks]);
                bf16x8 kl = *(const bf16x8*)(bl + nt * 4096 + koff[ks]);
                s0[nt] = MFMA16(kh, qh[0][ks], s0[nt]);
                s0[nt] = MFMA16(kh, ql[0][ks], s0[nt]);
                s0[nt] = MFMA16(kl, qh[0][ks], s0[nt]);
                s1[nt] = MFMA16(kh, qh[1][ks], s1[nt]);
                s1[nt] = MFMA16(kh, ql[1][ks], s1[nt]);
                s1[nt] = MFMA16(kl, qh[1][ks], s1[nt]);
            }
        }

        u32 pk0[4][2], pk1[4][2];
        float fsc0, fsc1;
        {   // softmax half 0
            float mloc = -3.0e38f;
            #pragma unroll
            for (int nt = 0; nt < 4; ++nt)
                #pragma unroll
                for (int r = 0; r < 4; ++r) mloc = fmaxf(mloc, s0[nt][r]);
            mloc = fmaxf(mloc, __shfl_xor(mloc, 16));
            mloc = fmaxf(mloc, __shfl_xor(mloc, 32));
            float mnew = fmaxf(m0, mloc);
            fsc0 = __expf(m0 - mnew);
            m0 = mnew;
            float ps = 0.f;
            #pragma unroll
            for (int nt = 0; nt < 4; ++nt) {
                float p0 = __expf(s0[nt][0] - mnew);
                float p1 = __expf(s0[nt][1] - mnew);
                float p2 = __expf(s0[nt][2] - mnew);
                float p3 = __expf(s0[nt][3] - mnew);
                ps += (p0 + p1) + (p2 + p3);
                pk0[nt][0] = pk2(p0, p1);
                pk0[nt][1] = pk2(p2, p3);
            }
            ps += __shfl_xor(ps, 16);
            ps += __shfl_xor(ps, 32);
            l0 = l0 * fsc0 + ps;
        }
        {   // softmax half 1
            float mloc = -3.0e38f;
            #pragma unroll
            for (int nt = 0; nt < 4; ++nt)
                #pragma unroll
                for (int r = 0; r < 4; ++r) mloc = fmaxf(mloc, s1[nt][r]);
            mloc = fmaxf(mloc, __shfl_xor(mloc, 16));
            mloc = fmaxf(mloc, __shfl_xor(mloc, 32));
            float mnew = fmaxf(m1, mloc);
            fsc1 = __expf(m1 - mnew);
            m1 = mnew;
            float ps = 0.f;
            #pragma unroll
            for (int nt = 0; nt < 4; ++nt) {
                float p0 = __expf(s1[nt][0] - mnew);
                float p1 = __expf(s1[nt][1] - mnew);
                float p2 = __expf(s1[nt][2] - mnew);
                float p3 = __expf(s1[nt][3] - mnew);
                ps += (p0 + p1) + (p2 + p3);
                pk1[nt][0] = pk2(p0, p1);
                pk1[nt][1] = pk2(p2, p3);
            }
            ps += __shfl_xor(ps, 16);
            ps += __shfl_xor(ps, 32);
            l1 = l1 * fsc1 + ps;
        }

        float fr0[4], fr1[4];
        #pragma unroll
        for (int r = 0; r < 4; ++r) {
            fr0[r] = __shfl(fsc0, 4 * g + r);
            fr1[r] = __shfl(fsc1, 4 * g + r);
        }
        #pragma unroll
        for (int dt = 0; dt < 8; ++dt)
            #pragma unroll
            for (int r = 0; r < 4; ++r) {
                O0[dt][r] *= fr0[r];
                O1[dt][r] *= fr1[r];
            }

        const int s0l = l15 | ((2 * (g & 1)) << 4);
        const int s1l = s0l + 16;
        const int hiH = g >> 1;
        #pragma unroll
        for (int kw = 0; kw < 2; ++kw) {
            u32 a0, a1, a2, a3, c0, c1, c2, c3;
            {
                u32 x0 = __shfl(pk0[2 * kw][0], s0l), y0 = __shfl(pk0[2 * kw + 1][0], s0l);
                u32 x1 = __shfl(pk0[2 * kw][1], s0l), y1 = __shfl(pk0[2 * kw + 1][1], s0l);
                u32 x2 = __shfl(pk0[2 * kw][0], s1l), y2 = __shfl(pk0[2 * kw + 1][0], s1l);
                u32 x3 = __shfl(pk0[2 * kw][1], s1l), y3 = __shfl(pk0[2 * kw + 1][1], s1l);
                a0 = hiH ? y0 : x0; a1 = hiH ? y1 : x1;
                a2 = hiH ? y2 : x2; a3 = hiH ? y3 : x3;
            }
            {
                u32 x0 = __shfl(pk1[2 * kw][0], s0l), y0 = __shfl(pk1[2 * kw + 1][0], s0l);
                u32 x1 = __shfl(pk1[2 * kw][1], s0l), y1 = __shfl(pk1[2 * kw + 1][1], s0l);
                u32 x2 = __shfl(pk1[2 * kw][0], s1l), y2 = __shfl(pk1[2 * kw + 1][0], s1l);
                u32 x3 = __shfl(pk1[2 * kw][1], s1l), y3 = __shfl(pk1[2 * kw + 1][1], s1l);
                c0 = hiH ? y0 : x0; c1 = hiH ? y1 : x1;
                c2 = hiH ? y2 : x2; c3 = hiH ? y3 : x3;
            }
            union { u32 w[4]; bf16x8 v; } pa, pb;
            pa.w[0] = a0; pa.w[1] = a1; pa.w[2] = a2; pa.w[3] = a3;
            pb.w[0] = c0; pb.w[1] = c1; pb.w[2] = c2; pb.w[3] = c3;
            #pragma unroll
            for (int dt = 0; dt < 8; ++dt) {
                bf16x8 vf = *(const bf16x8*)(bv + (16 * dt + l15) * 128 + voff[kw]);
                O0[dt] = MFMA16(pa.v, vf, O0[dt]);
                O1[dt] = MFMA16(pb.v, vf, O1[dt]);
            }
        }

        __syncthreads();
        buf ^= 1;
    }

    u16* op = opart + ((size_t)z * 16384 + q0row) * DH;
    #pragma unroll
    for (int dt = 0; dt < 8; ++dt)
        #pragma unroll
        for (int r = 0; r < 4; ++r) {
            op[(size_t)(4 * g + r) * DH + 16 * dt + l15]      = bf16_rn(O0[dt][r]);
            op[(size_t)(16 + 4 * g + r) * DH + 16 * dt + l15] = bf16_rn(O1[dt][r]);
        }
    if (lane < 16) {
        ml[(size_t)z * 16384 + q0row + lane]      = make_float2(m0, l0);
        ml[(size_t)z * 16384 + q0row + 16 + lane] = make_float2(m1, l1);
    }
}

// ---------------- Kernel 3: merge the four kt-quarters (unchanged) ----------------
__global__ __launch_bounds__(256) void merge4(
    const u16* __restrict__ op, const float2* __restrict__ ml, float* __restrict__ O)
{
    int row = blockIdx.x * 16 + (threadIdx.x >> 4);
    int dq  = (threadIdx.x & 15) * 8;
    float2 a[4];
    #pragma unroll
    for (int zz = 0; zz < 4; ++zz) a[zz] = ml[(size_t)zz * 16384 + row];
    float M = fmaxf(fmaxf(a[0].x, a[1].x), fmaxf(a[2].x, a[3].x));
    float w[4], den = 0.f;
    #pragma unroll
    for (int zz = 0; zz < 4; ++zz) {
        w[zz] = __expf(a[zz].x - M);
        den += a[zz].y * w[zz];
    }
    float inv = 1.0f / den;
    float acc[8];
    #pragma unroll
    for (int j = 0; j < 8; ++j) acc[j] = 0.f;
    #pragma unroll
    for (int zz = 0; zz < 4; ++zz) {
        const u16* p = op + ((size_t)zz * 16384 + row) * DH + dq;
        bf16x8 vv = *(const bf16x8*)p;
        #pragma unroll
        for (int j = 0; j < 8; ++j) acc[j] += w[zz] * bf16_f((u16)vv[j]);
    }
    float4 oa, ob;
    oa.x = acc[0] * inv; oa.y = acc[1] * inv; oa.z = acc[2] * inv; oa.w = acc[3] * inv;
    ob.x = acc[4] * inv; ob.y = acc[5] * inv; ob.z = acc[6] * inv; ob.w = acc[7] * inv;
    *(float4*)(O + (size_t)row * DH + dq)     = oa;
    *(float4*)(O + (size_t)row * DH + dq + 4) = ob;
}

extern "C" void kernel_launch(void* const* d_in, const int* in_sizes, int n_in,
                              void* d_out, int out_size, void* d_ws, size_t ws_size,
                              hipStream_t stream) {
    const float* x  = (const float*)d_in[0];
    const float* Wq = (const float*)d_in[1];
    const float* Wk = (const float*)d_in[2];
    const float* Wv = (const float*)d_in[3];
    float* out = (float*)d_out;

    const size_t SZ = (size_t)B_ * S_ * DH;     // 2,097,152 elems (4 MiB bf16 each)
    u16* qhi = (u16*)d_ws;
    u16* qlo = qhi + SZ;
    u16* khi = qlo + SZ;
    u16* klo = khi + SZ;
    u16* vtp = klo + SZ;
    u16* wpk = vtp + SZ;                        // 1.25 MiB staging image
    u16*    opart = (u16*)((char*)wpk + 1310720);   // 16 MiB bf16 partials
    float2* mlp   = (float2*)((char*)opart + (size_t)4 * 16384 * 128 * 2);
    // total = 20.97M + 1.31M + 16.78M + 0.52M = 39.58 MB  (== round-3 proven bound)

    wconv2<<<320, 256, 0, stream>>>(Wq, Wk, Wv, wpk);
    qkv_v4<<<256, 256, 0, stream>>>(x, wpk, qhi, qlo, khi, klo, vtp);
    flash4<<<256, 512, 0, stream>>>(qhi, qlo, khi, klo, vtp, opart, mlp);
    merge4<<<1024, 256, 0, stream>>>(opart, mlp, out);
}